// Round 1
// baseline (4563.177 us; speedup 1.0000x reference)
//
#include <hip/hip_runtime.h>
#include <math.h>

#define BB 32
#define JJ 2048
#define II 16
#define NN 64
#define DD 32
#define JC 32      // j's per block
#define NTHREADS 512

// Dot of 16 floats (x in 4 float4 regs, W loaded here) with 4 independent chains for ILP.
__device__ __forceinline__ float dot16(const float4 x0, const float4 x1,
                                       const float4 x2, const float4 x3,
                                       const float4* __restrict__ wp) {
    float4 w0 = wp[0], w1 = wp[1], w2 = wp[2], w3 = wp[3];
    float a = w0.x * x0.x, b = w0.y * x0.y, c = w0.z * x0.z, d = w0.w * x0.w;
    a = fmaf(w1.x, x1.x, a); b = fmaf(w1.y, x1.y, b);
    c = fmaf(w1.z, x1.z, c); d = fmaf(w1.w, x1.w, d);
    a = fmaf(w2.x, x2.x, a); b = fmaf(w2.y, x2.y, b);
    c = fmaf(w2.z, x2.z, c); d = fmaf(w2.w, x2.w, d);
    a = fmaf(w3.x, x3.x, a); b = fmaf(w3.y, x3.y, b);
    c = fmaf(w3.z, x3.z, c); d = fmaf(w3.w, x3.w, d);
    return (a + b) + (c + d);
}

// One routing pass over W. MODE 0: c = 1/64 uniform (first iteration, b-logits all 0).
// MODE 1: logits = <vsum, u_hat> per (b,n,j), c = softmax over n, computed in-block.
// Accumulates s[b,n,d] via atomics. u_hat recomputed on the fly (cheaper than storing 512MB).
template <int MODE>
__global__ __launch_bounds__(NTHREADS)
void caps_pass(const float* __restrict__ x, const float* __restrict__ W,
               const float* __restrict__ vsum, float* __restrict__ s) {
    __shared__ float xs[JC * II];        // x[b, j0:j0+JC, :]
    __shared__ float wmax[2][8];         // per-wave softmax max, double-buffered by j parity
    __shared__ float wsum[2][8];         // per-wave softmax expsum

    const int b  = blockIdx.x;
    const int j0 = blockIdx.y * JC;
    const int t  = threadIdx.x;
    const int n  = t >> 3;               // capsule 0..63
    const int dg = t & 7;                // d-group: this thread owns d = dg*4 .. dg*4+3
    const int lane = t & 63;
    const int w  = t >> 6;               // wave 0..7 (wave w holds n = 8w..8w+7)

    // stage x tile: JC*II = 512 floats, one per thread, coalesced
    xs[t] = x[(size_t)b * JJ * II + (size_t)j0 * II + t];

    float vv0 = 0.f, vv1 = 0.f, vv2 = 0.f, vv3 = 0.f;
    if (MODE) {
        const float* vp = vsum + ((size_t)b * NN + n) * DD + dg * 4;
        vv0 = vp[0]; vv1 = vp[1]; vv2 = vp[2]; vv3 = vp[3];
    }
    __syncthreads();

    float sacc0 = 0.f, sacc1 = 0.f, sacc2 = 0.f, sacc3 = 0.f;

    for (int jj = 0; jj < JC; ++jj) {
        const int j = j0 + jj;
        const float4* xp = (const float4*)(xs + jj * II);
        const float4 x0 = xp[0], x1 = xp[1], x2 = xp[2], x3 = xp[3];

        // u_hat[b, n, j, dg*4+k] for k=0..3
        const float4* wp =
            (const float4*)(W + ((size_t)(n * JJ + j) * DD + dg * 4) * II);
        float uh0 = dot16(x0, x1, x2, x3, wp + 0);
        float uh1 = dot16(x0, x1, x2, x3, wp + 4);
        float uh2 = dot16(x0, x1, x2, x3, wp + 8);
        float uh3 = dot16(x0, x1, x2, x3, wp + 12);

        float c;
        if (MODE) {
            // logit[b,n,j] = sum_d vsum[b,n,d] * u_hat[b,n,j,d]
            float lp = uh0 * vv0 + uh1 * vv1 + uh2 * vv2 + uh3 * vv3;
            lp += __shfl_xor(lp, 1);
            lp += __shfl_xor(lp, 2);
            lp += __shfl_xor(lp, 4);     // full logit on all 8 lanes of the n-octet

            // max over this wave's 8 n values (octets at lane^8,^16,^32)
            float m = lp;
            m = fmaxf(m, __shfl_xor(m, 8));
            m = fmaxf(m, __shfl_xor(m, 16));
            m = fmaxf(m, __shfl_xor(m, 32));
            const int par = jj & 1;
            if (lane == 0) wmax[par][w] = m;
            __syncthreads();
            float gm = wmax[par][0];
            #pragma unroll
            for (int q = 1; q < 8; ++q) gm = fmaxf(gm, wmax[par][q]);

            float e = __expf(lp - gm);
            // sum over this wave's 8 n values (exact: xor 8/16/32 visits each octet once)
            float es = e;
            es += __shfl_xor(es, 8);
            es += __shfl_xor(es, 16);
            es += __shfl_xor(es, 32);
            if (lane == 0) wsum[par][w] = es;
            __syncthreads();
            float tot = wsum[par][0];
            #pragma unroll
            for (int q = 1; q < 8; ++q) tot += wsum[par][q];
            c = e / tot;
        } else {
            c = 1.0f / 64.0f;
        }

        sacc0 = fmaf(c, uh0, sacc0);
        sacc1 = fmaf(c, uh1, sacc1);
        sacc2 = fmaf(c, uh2, sacc2);
        sacc3 = fmaf(c, uh3, sacc3);
    }

    float* sp = s + ((size_t)b * NN + n) * DD + dg * 4;
    atomicAdd(sp + 0, sacc0);
    atomicAdd(sp + 1, sacc1);
    atomicAdd(sp + 2, sacc2);
    atomicAdd(sp + 3, sacc3);
}

// v = squash(s); writes v to out (last call leaves final v2) and accumulates vsum += v
// (so the next pass's logits use v0, then v0+v1 — exploits linearity of the b update).
__global__ __launch_bounds__(256)
void caps_squash(const float* __restrict__ s, float* __restrict__ vsum,
                 float* __restrict__ out) {
    const int idx = blockIdx.x * 256 + threadIdx.x;   // 0 .. B*N*D-1
    const float sv = s[idx];
    float sq = sv * sv;
    // sum of squares over the 32 d's (rows are 32-lane aligned within the wave)
    sq += __shfl_xor(sq, 1);
    sq += __shfl_xor(sq, 2);
    sq += __shfl_xor(sq, 4);
    sq += __shfl_xor(sq, 8);
    sq += __shfl_xor(sq, 16);
    const float s2 = sq;
    const float scale = s2 / (1.0f + s2) / sqrtf(s2 + 1e-7f);
    const float v = scale * sv;
    out[idx] = v;
    vsum[idx] += v;
}

extern "C" void kernel_launch(void* const* d_in, const int* in_sizes, int n_in,
                              void* d_out, int out_size, void* d_ws, size_t ws_size,
                              hipStream_t stream) {
    const float* x = (const float*)d_in[0];   // [32,2048,16]
    const float* W = (const float*)d_in[1];   // [64,2048,32,16]
    float* out = (float*)d_out;               // [32,64,32]

    float* s    = (float*)d_ws;               // B*N*D floats
    float* vsum = s + BB * NN * DD;           // B*N*D floats

    const size_t sbytes = (size_t)BB * NN * DD * sizeof(float);

    dim3 grid(BB, JJ / JC);
    const int sqblocks = (BB * NN * DD) / 256;

    // zero s and vsum (ws is poisoned 0xAA before every launch)
    hipMemsetAsync(s, 0, 2 * sbytes, stream);

    // r = 0: c uniform
    caps_pass<0><<<grid, NTHREADS, 0, stream>>>(x, W, vsum, s);
    caps_squash<<<sqblocks, 256, 0, stream>>>(s, vsum, out);   // v0; vsum = v0

    // r = 1: logits = <v0, u_hat>
    hipMemsetAsync(s, 0, sbytes, stream);
    caps_pass<1><<<grid, NTHREADS, 0, stream>>>(x, W, vsum, s);
    caps_squash<<<sqblocks, 256, 0, stream>>>(s, vsum, out);   // v1; vsum = v0+v1

    // r = 2: logits = <v0+v1, u_hat>  (b2 = b1 + <v1,u> by linearity)
    hipMemsetAsync(s, 0, sbytes, stream);
    caps_pass<1><<<grid, NTHREADS, 0, stream>>>(x, W, vsum, s);
    caps_squash<<<sqblocks, 256, 0, stream>>>(s, vsum, out);   // v2 -> d_out
}

// Round 4
// 3286.109 us; speedup vs baseline: 1.3886x; 1.3886x over previous
//
#include <hip/hip_runtime.h>
#include <math.h>

#define JJ 2048
#define II 16
#define NN 64
#define DD 32
#define BBATCH 32

#define JC 16        // j's per block
#define THREADS 512  // 8 waves: (bq 0..3) x (dh 0..1), lane = n
#define BSUB 16      // batches per block (half of 32)

typedef unsigned int u32;

__device__ __forceinline__ void gload_lds16(const void* g, void* l) {
    __builtin_amdgcn_global_load_lds(
        (const __attribute__((address_space(1))) u32*)g,
        (__attribute__((address_space(3))) u32*)l, 16, 0, 0);
}

// One routing pass. W streamed once: block = (j-chunk, batch-half), covers all n (lane=n)
// and all d. W k-quarters (32KB) pipelined via 4 LDS buffers + global_load_lds with
// counted vmcnt(4); 2-barrier separation between a buffer's ds_reads and its overwrite.
// LDS d-slot XOR-swizzled (source-side pre-swizzle, linear dest — rule 21) to kill the
// 64-way bank conflict of lane-stride-2048B ds_read_b128.
template <int MODE>
__global__ __launch_bounds__(THREADS, 2)
void caps_pass(const float* __restrict__ xg, const float* __restrict__ Wg,
               const float* __restrict__ vsumg, float* __restrict__ s)
{
    __shared__ float qb0[NN * DD * 4];   // 32KB: [n][d-slot swizzled][4 k] (one k-quarter)
    __shared__ float qb1[NN * DD * 4];
    __shared__ float qb2[NN * DD * 4];
    __shared__ float qb3[NN * DD * 4];
    __shared__ float xs[BSUB * JC * II]; // 16KB: [bl*16+jj][16 k]
    __shared__ float lpb[2][BSUB][NN];   // 8KB: partial logits per d-half

    const int t    = threadIdx.x;
    const int lane = t & 63;             // n (capsule)
    const int w    = t >> 6;             // wave 0..7
    const int bq   = w >> 1;             // b-quad 0..3 (4 b each)
    const int dh   = w & 1;              // d-half 0..1 (16 d each)
    const int n    = lane;

    // XCD pairing: both batch-halves of a j-chunk land on the same XCD (id%8 = jc%8)
    const int id = blockIdx.x;
    const int jc = (id & 7) + ((id >> 4) << 3);   // 0..127
    const int bh = (id >> 3) & 1;
    const int j0 = jc * JC;
    const int b0 = bh * BSUB;

    // vsum -> registers (constant across the whole pass), then drain vmcnt so the
    // pipeline's counted vmcnt(4) is exact.
    float vs[4][16];
    if (MODE) {
        #pragma unroll
        for (int bb = 0; bb < 4; ++bb) {
            const float* vp = vsumg + ((size_t)(b0 + bq * 4 + bb) * NN + n) * DD + dh * 16;
            #pragma unroll
            for (int dq = 0; dq < 4; ++dq) {
                const float4 v4 = *(const float4*)(vp + dq * 4);
                vs[bb][dq * 4 + 0] = v4.x; vs[bb][dq * 4 + 1] = v4.y;
                vs[bb][dq * 4 + 2] = v4.z; vs[bb][dq * 4 + 3] = v4.w;
            }
        }
    }
    asm volatile("s_waitcnt vmcnt(0)" ::: "memory");
    if (MODE) {
        // Phantom use: pins the compiler's own waitcnt for the vs loads HERE (prologue),
        // so it never inserts a conservative vmcnt(0) inside the pipelined loop.
        #pragma unroll
        for (int bb = 0; bb < 4; ++bb)
            #pragma unroll
            for (int dd = 0; dd < 16; ++dd)
                asm volatile("" :: "v"(vs[bb][dd]));
    }

    // stage x tile (16KB): dest linear in thread id (broadcast reads -> no swizzle needed)
    #pragma unroll
    for (int it = 0; it < 2; ++it) {
        const int T = t + it * THREADS;       // 0..1023
        const int p = T >> 2, quad = T & 3;   // p = bl*16+jj
        const int bl = p >> 4, jj = p & 15;
        const float* src = xg + ((size_t)(b0 + bl) * JJ + (j0 + jj)) * II + quad * 4;
        gload_lds16(src, xs + (size_t)T * 4);
    }

    // quarter issue: quarter Q = jj*4+q ; 4 x gload_lds(16B) per thread = 32KB total.
    // Source pre-swizzled: linear LDS slot dsl holds global d = dsl ^ (n&7).
    auto issueQ = [&](int Qi, float* buf) {
        const int Q  = Qi > 63 ? 63 : Qi;     // tail clamp keeps vmcnt counts uniform
        const int jq = Q >> 2, q = Q & 3;
        #pragma unroll
        for (int it = 0; it < 4; ++it) {
            const int T    = t + it * THREADS;   // 0..2047
            const int nrow = T >> 5;             // 0..63
            const int dsl  = T & 31;             // swizzled slot
            const int d    = dsl ^ (nrow & 7);
            const float* src = Wg + ((size_t)nrow * JJ + (j0 + jq)) * (DD * II) + d * II + q * 4;
            gload_lds16(src, buf + (size_t)T * 4);
        }
    };

    float uh[4][16];    // u_hat for current j
    float sacc[4][16];  // s accumulator over the j-chunk
    #pragma unroll
    for (int bb = 0; bb < 4; ++bb)
        #pragma unroll
        for (int dd = 0; dd < 16; ++dd) { uh[bb][dd] = 0.f; sacc[bb][dd] = 0.f; }

    auto computeQ = [&](int jj, int q, const float* buf) {
        float4 xq[4];
        #pragma unroll
        for (int bb = 0; bb < 4; ++bb)   // same addr across all lanes -> LDS broadcast
            xq[bb] = ((const float4*)xs)[((bq * 4 + bb) * JC + jj) * 4 + q];
        const float4* bv = (const float4*)buf;
        // dd processed in 4 groups of 4 to bound live ds_read results (VGPR pressure);
        // all indexing compile-time-constant (rule 20).
        #pragma unroll
        for (int dg = 0; dg < 4; ++dg) {
            float4 wv[4];
            #pragma unroll
            for (int u = 0; u < 4; ++u) {
                const int dd = dg * 4 + u;
                const int slot = (dh * 16 + dd) ^ (n & 7);
                wv[u] = bv[n * 32 + slot];
            }
            #pragma unroll
            for (int u = 0; u < 4; ++u) {
                const int dd = dg * 4 + u;
                #pragma unroll
                for (int bb = 0; bb < 4; ++bb) {
                    uh[bb][dd] = fmaf(wv[u].x, xq[bb].x, uh[bb][dd]);
                    uh[bb][dd] = fmaf(wv[u].y, xq[bb].y, uh[bb][dd]);
                    uh[bb][dd] = fmaf(wv[u].z, xq[bb].z, uh[bb][dd]);
                    uh[bb][dd] = fmaf(wv[u].w, xq[bb].w, uh[bb][dd]);
                }
            }
        }
    };

    auto finishJ = [&]() {
        if (MODE) {
            float lp[4];
            #pragma unroll
            for (int bb = 0; bb < 4; ++bb) {
                float acc = 0.f;
                #pragma unroll
                for (int dd = 0; dd < 16; ++dd) acc = fmaf(uh[bb][dd], vs[bb][dd], acc);
                lp[bb] = acc;
                lpb[dh][bq * 4 + bb][n] = acc;   // publish d-half partial
            }
            asm volatile("s_waitcnt lgkmcnt(0)" ::: "memory");
            __builtin_amdgcn_s_barrier();
            asm volatile("" ::: "memory");
            #pragma unroll
            for (int bb = 0; bb < 4; ++bb) lp[bb] += lpb[1 - dh][bq * 4 + bb][n];
            #pragma unroll
            for (int bb = 0; bb < 4; ++bb) {
                float m = lp[bb];
                #pragma unroll
                for (int off = 1; off < 64; off <<= 1) m = fmaxf(m, __shfl_xor(m, off));
                const float e = __expf(lp[bb] - m);
                float es = e;
                #pragma unroll
                for (int off = 1; off < 64; off <<= 1) es += __shfl_xor(es, off);
                const float c = e / es;
                #pragma unroll
                for (int dd = 0; dd < 16; ++dd) {
                    sacc[bb][dd] = fmaf(c, uh[bb][dd], sacc[bb][dd]);
                    uh[bb][dd] = 0.f;
                }
            }
        } else {
            #pragma unroll
            for (int bb = 0; bb < 4; ++bb)
                #pragma unroll
                for (int dd = 0; dd < 16; ++dd) {
                    sacc[bb][dd] += uh[bb][dd];
                    uh[bb][dd] = 0.f;
                }
        }
    };

    // 4-buffer quarter pipeline, prefetch depth 2; raw s_barrier (no drain), counted
    // vmcnt(4). Buffer overwritten 2 barriers after its last ds_read.
    float* bufs[4] = { qb0, qb1, qb2, qb3 };
    issueQ(0, bufs[0]);
    issueQ(1, bufs[1]);

    for (int jj = 0; jj < JC; ++jj) {
        #pragma unroll
        for (int q = 0; q < 4; ++q) {
            const int k = jj * 4 + q;
            asm volatile("s_waitcnt vmcnt(4)" ::: "memory");  // quarter k landed
            __builtin_amdgcn_s_barrier();                     // all waves see it
            asm volatile("" ::: "memory");
            // (k+2)&3 == (q+2)&3 and k&3 == q since jj*4 ≡ 0 (mod 4): explicit static
            // indices so the bufs[] array can never be demoted to scratch (rule 20).
            issueQ(k + 2, bufs[(q + 2) & 3]);
            computeQ(jj, q, bufs[q]);
        }
        finishJ();
    }

    const float cs = MODE ? 1.0f : (1.0f / 64.0f);
    #pragma unroll
    for (int bb = 0; bb < 4; ++bb) {
        float* sp = s + ((size_t)(b0 + bq * 4 + bb) * NN + n) * DD + dh * 16;
        #pragma unroll
        for (int dd = 0; dd < 16; ++dd)
            atomicAdd(sp + dd, sacc[bb][dd] * cs);
    }
}

// v = squash(s); out = v; vsum += v (linearized-logit trick: pass r uses <v0+..+v_{r-1}, u>)
__global__ __launch_bounds__(256)
void caps_squash(const float* __restrict__ s, float* __restrict__ vsum,
                 float* __restrict__ out) {
    const int idx = blockIdx.x * 256 + threadIdx.x;   // 0 .. B*N*D-1
    const float sv = s[idx];
    float sq = sv * sv;
    sq += __shfl_xor(sq, 1);
    sq += __shfl_xor(sq, 2);
    sq += __shfl_xor(sq, 4);
    sq += __shfl_xor(sq, 8);
    sq += __shfl_xor(sq, 16);
    const float s2 = sq;
    const float scale = s2 / (1.0f + s2) / sqrtf(s2 + 1e-7f);
    const float v = scale * sv;
    out[idx] = v;
    vsum[idx] += v;
}

extern "C" void kernel_launch(void* const* d_in, const int* in_sizes, int n_in,
                              void* d_out, int out_size, void* d_ws, size_t ws_size,
                              hipStream_t stream) {
    const float* x = (const float*)d_in[0];   // [32,2048,16]
    const float* W = (const float*)d_in[1];   // [64,2048,32,16]
    float* out = (float*)d_out;               // [32,64,32]

    float* s    = (float*)d_ws;               // B*N*D floats
    float* vsum = s + BBATCH * NN * DD;       // B*N*D floats

    const size_t sbytes = (size_t)BBATCH * NN * DD * sizeof(float);
    const int sqblocks = (BBATCH * NN * DD) / 256;

    hipMemsetAsync(s, 0, 2 * sbytes, stream);

    // r = 0: c uniform (1/64)
    caps_pass<0><<<256, THREADS, 0, stream>>>(x, W, vsum, s);
    caps_squash<<<sqblocks, 256, 0, stream>>>(s, vsum, out);   // v0; vsum = v0

    // r = 1: logits = <v0, u_hat>
    hipMemsetAsync(s, 0, sbytes, stream);
    caps_pass<1><<<256, THREADS, 0, stream>>>(x, W, vsum, s);
    caps_squash<<<sqblocks, 256, 0, stream>>>(s, vsum, out);   // v1; vsum = v0+v1

    // r = 2: logits = <v0+v1, u_hat>
    hipMemsetAsync(s, 0, sbytes, stream);
    caps_pass<1><<<256, THREADS, 0, stream>>>(x, W, vsum, s);
    caps_squash<<<sqblocks, 256, 0, stream>>>(s, vsum, out);   // v2 -> d_out
}